// Round 1
// baseline (1665.063 us; speedup 1.0000x reference)
//
#include <hip/hip_runtime.h>

// LapCluster fused fp32 pipeline for MI355X.
// B=8, N=16384, K=28. Clusters: values always in [0,16) (randint high=min(NUM_CLUSTER)).
// Pool trick: concat([f3, pool]) feeding the next 1x1 conv is split as
//   W*[f3,pool] = W[:, :128]*f3 + poolc[o][cluster],  poolc precomputed per batch.
// All ReLU outputs >= 0 -> float-bits unsigned atomicMax is exact, 0-init valid.

#define TPB 512          // 8 waves
#define PT 64            // points per tile == wave size
#define NPB 16384        // N per batch
#define NPTS 131072      // B*N
#define NC 16
#define NBLK 512         // grid for k0/kmid (4 tiles each, 64 blocks/batch)
#define NBLK3 1024       // grid for k3 (2 tiles each, 128 blocks/batch)

__device__ __forceinline__ float relu_(float v) { return fmaxf(v, 0.f); }

// acc[j] += sum_k W[(row0+j)*STRIDE + k] * Ain[k][lane], Ain is LDS [K][PT].
// Wrow0 indices are wave-uniform -> scalar loads.
template<int K, int CPT, int STRIDE>
__device__ __forceinline__ void accum_lds(float* acc, const float* Ain,
                                          const float* __restrict__ Wrow0, int lane) {
  for (int k0 = 0; k0 < K; k0 += 8) {
    float a[8];
#pragma unroll
    for (int kk = 0; kk < 8; ++kk) a[kk] = Ain[(k0 + kk) * PT + lane];
#pragma unroll
    for (int j = 0; j < CPT; ++j) {
#pragma unroll
      for (int kk = 0; kk < 8; ++kk)
        acc[j] = fmaf(Wrow0[j * STRIDE + k0 + kk], a[kk], acc[j]);
    }
  }
}

// Stage 0: x -> f256 -> f64 -> f128 (write global) + partial pool(clusters[0])
__global__ void __launch_bounds__(TPB) k0_kern(
    const float* __restrict__ x, const int* __restrict__ cls,
    const float* __restrict__ w_in, const float* __restrict__ b_in,
    const float* __restrict__ w1, const float* __restrict__ b1,
    const float* __restrict__ w2, const float* __restrict__ b2,
    float* __restrict__ f128g, float* __restrict__ part0) {
  __shared__ float Ach[128 * PT];        // f256 chunk; later holds A64 (first 64*PT)
  __shared__ unsigned pool_s[NC * 128];
  const int tid = threadIdx.x;
  const int lane = tid & 63;
  const int g = __builtin_amdgcn_readfirstlane(tid >> 6);
  const int b = blockIdx.x >> 6;        // 64 blocks per batch
  for (int i = tid; i < NC * 128; i += TPB) pool_s[i] = 0u;

  for (int t = 0; t < 4; ++t) {
    const int pg = (blockIdx.x * 4 + t) * PT + lane;
    const int n = pg & (NPB - 1);
    float xr[28];
    {
      const float4* xp = reinterpret_cast<const float4*>(x + (size_t)pg * 28);
#pragma unroll
      for (int q = 0; q < 7; ++q) {
        float4 v = xp[q];
        xr[4 * q] = v.x; xr[4 * q + 1] = v.y; xr[4 * q + 2] = v.z; xr[4 * q + 3] = v.w;
      }
    }
    float acc64[8];
#pragma unroll
    for (int j = 0; j < 8; ++j) acc64[j] = b1[g * 8 + j];

    for (int c = 0; c < 2; ++c) {
      {  // f256 chunk c: channels [c*128, c*128+128), CPT=16 per wave
        const int o0 = c * 128 + g * 16;
        float acc[16];
#pragma unroll
        for (int j = 0; j < 16; ++j) acc[j] = b_in[o0 + j];
#pragma unroll
        for (int k = 0; k < 28; ++k) {
#pragma unroll
          for (int j = 0; j < 16; ++j)
            acc[j] = fmaf(w_in[(o0 + j) * 28 + k], xr[k], acc[j]);
        }
#pragma unroll
        for (int j = 0; j < 16; ++j) Ach[(g * 16 + j) * PT + lane] = relu_(acc[j]);
      }
      __syncthreads();
      accum_lds<128, 8, 256>(acc64, Ach, w1 + (g * 8) * 256 + c * 128, lane);
      __syncthreads();
    }
    // A64 aliases Ach (all f64 reads of Ach are done)
#pragma unroll
    for (int j = 0; j < 8; ++j) Ach[(g * 8 + j) * PT + lane] = relu_(acc64[j]);
    __syncthreads();
    {  // w2: 64 -> 128, write + pool
      const int o0 = g * 16;
      float acc[16];
#pragma unroll
      for (int j = 0; j < 16; ++j) acc[j] = b2[o0 + j];
      accum_lds<64, 16, 64>(acc, Ach, w2 + o0 * 64, lane);
      const int cl = cls[pg];
#pragma unroll
      for (int j = 0; j < 16; ++j) {
        float v = relu_(acc[j]);
        f128g[(b * 128 + o0 + j) * NPB + n] = v;
        atomicMax(&pool_s[cl * 128 + o0 + j], __float_as_uint(v));
      }
    }
    __syncthreads();  // protect Ach rewrite next tile
  }
  for (int i = tid; i < NC * 128; i += TPB)
    part0[(size_t)blockIdx.x * 2048 + i] = __uint_as_float(pool_s[i]);
}

// Stages 1,2: f128 -> f3(w3[S-1]) ; f64 = w1[S]*[f3, pool_{S-1}] ; f128' = w2[S] ; pool(clusters[S])
__global__ void __launch_bounds__(TPB) kmid_kern(
    float* __restrict__ f128g,
    const float* __restrict__ part_prev, float* __restrict__ part_cur,
    const int* __restrict__ cls,
    const float* __restrict__ w3, const float* __restrict__ b3,
    const float* __restrict__ w1, const float* __restrict__ b1,
    const float* __restrict__ w2, const float* __restrict__ b2,
    int S) {
  __shared__ float A128s[128 * PT];
  __shared__ float F3ch[64 * PT];      // pf in preamble; f3 chunk; A64 at end
  __shared__ float poolc[64 * NC];
  __shared__ unsigned pool_s[NC * 128];
  const int tid = threadIdx.x;
  const int lane = tid & 63;
  const int g = __builtin_amdgcn_readfirstlane(tid >> 6);
  const int b = blockIdx.x >> 6;
  const float* w3s = w3 + (S - 1) * 128 * 128;
  const float* b3s = b3 + (S - 1) * 128;
  const float* w1s = w1 + S * 64 * 256;
  const float* b1s = b1 + S * 64;
  const float* w2s = w2 + S * 128 * 64;
  const float* b2s = b2 + S * 128;
  const int* clg = cls + (S - 1) * NPTS;
  const int* clp = cls + S * NPTS;
  for (int i = tid; i < NC * 128; i += TPB) pool_s[i] = 0u;

  float* pf = F3ch;   // [16][128] pooled maxima
  for (int i = tid; i < 2048; i += TPB) {
    float m = 0.f;
    const float* pp = part_prev + (size_t)(b * 64) * 2048 + i;
    for (int jj = 0; jj < 64; ++jj) m = fmaxf(m, pp[(size_t)jj * 2048]);
    pf[i] = m;
  }
  __syncthreads();
  for (int e = tid; e < 1024; e += TPB) {   // poolc[o][cl] incl. bias
    const int o = e >> 4, cl = e & 15;
    float s = b1s[o];
    const float* wr = w1s + o * 256 + 128;
    const float* pr = pf + cl * 128;
    for (int k = 0; k < 128; ++k) s = fmaf(wr[k], pr[k], s);
    poolc[e] = s;
  }
  __syncthreads();

  for (int t = 0; t < 4; ++t) {
    const int pg0 = (blockIdx.x * 4 + t) * PT;
    const int n0 = pg0 & (NPB - 1);
    {  // stage f128 tile (float4)
      const float4* src = reinterpret_cast<const float4*>(f128g + (size_t)b * 128 * NPB + n0);
      float4* dst = reinterpret_cast<float4*>(A128s);
      for (int i4 = tid; i4 < 128 * (PT / 4); i4 += TPB) {
        const int r = i4 >> 4, q = i4 & 15;
        dst[i4] = src[r * (NPB / 4) + q];
      }
    }
    const int cg = clg[pg0 + lane];
    const int cp = clp[pg0 + lane];
    float acc64[8];
#pragma unroll
    for (int j = 0; j < 8; ++j) acc64[j] = poolc[(g * 8 + j) * NC + cg];
    __syncthreads();
    for (int c = 0; c < 2; ++c) {
      {  // f3 chunk c: channels [c*64, c*64+64)
        const int oc = c * 64 + g * 8;
        float acc[8];
#pragma unroll
        for (int j = 0; j < 8; ++j) acc[j] = b3s[oc + j];
        accum_lds<128, 8, 128>(acc, A128s, w3s + oc * 128, lane);
#pragma unroll
        for (int j = 0; j < 8; ++j) F3ch[(g * 8 + j) * PT + lane] = relu_(acc[j]);
      }
      __syncthreads();
      accum_lds<64, 8, 256>(acc64, F3ch, w1s + (g * 8) * 256 + c * 64, lane);
      __syncthreads();
    }
#pragma unroll
    for (int j = 0; j < 8; ++j) F3ch[(g * 8 + j) * PT + lane] = relu_(acc64[j]);  // A64
    __syncthreads();
    {  // w2: 64 -> 128, in-place write + pool
      const int o0 = g * 16;
      float acc[16];
#pragma unroll
      for (int j = 0; j < 16; ++j) acc[j] = b2s[o0 + j];
      accum_lds<64, 16, 64>(acc, F3ch, w2s + o0 * 64, lane);
#pragma unroll
      for (int j = 0; j < 16; ++j) {
        float v = relu_(acc[j]);
        f128g[(b * 128 + o0 + j) * NPB + n0 + lane] = v;
        atomicMax(&pool_s[cp * 128 + o0 + j], __float_as_uint(v));
      }
    }
    __syncthreads();
  }
  for (int i = tid; i < NC * 128; i += TPB)
    part_cur[(size_t)blockIdx.x * 2048 + i] = __uint_as_float(pool_s[i]);
}

// Head: f128 -> f3(w3[2]) ; o1 = w_out1*[f3,pool2] ; o2 = w_out2*o1 ; global max -> out
__global__ void __launch_bounds__(TPB) k3_kern(
    const float* __restrict__ f128g, const float* __restrict__ part2,
    const int* __restrict__ cls,
    const float* __restrict__ w3, const float* __restrict__ b3,
    const float* __restrict__ wo1, const float* __restrict__ bo1,
    const float* __restrict__ wo2, const float* __restrict__ bo2,
    float* __restrict__ out) {
  __shared__ float A128s[128 * PT];    // also O1
  __shared__ float F3ch[64 * PT];      // also pf
  __shared__ float poolco[128 * NC];
  const int tid = threadIdx.x;
  const int lane = tid & 63;
  const int g = __builtin_amdgcn_readfirstlane(tid >> 6);
  const int b = blockIdx.x >> 7;       // 128 blocks per batch
  const float* w3s = w3 + 2 * 128 * 128;
  const float* b3s = b3 + 2 * 128;
  const int* clg = cls + 2 * NPTS;

  float* pf = F3ch;
  for (int i = tid; i < 2048; i += TPB) {
    float m = 0.f;
    const float* pp = part2 + (size_t)(b * 64) * 2048 + i;
    for (int jj = 0; jj < 64; ++jj) m = fmaxf(m, pp[(size_t)jj * 2048]);
    pf[i] = m;
  }
  __syncthreads();
  for (int e = tid; e < 2048; e += TPB) {   // poolco[o][cl] incl. bias, o<128
    const int o = e >> 4, cl = e & 15;
    float s = bo1[o];
    const float* wr = wo1 + o * 256 + 128;
    const float* pr = pf + cl * 128;
    for (int k = 0; k < 128; ++k) s = fmaf(wr[k], pr[k], s);
    poolco[e] = s;
  }
  __syncthreads();
  const int o0 = g * 16;
  float omax[16];
#pragma unroll
  for (int j = 0; j < 16; ++j) omax[j] = 0.f;

  for (int t = 0; t < 2; ++t) {
    const int pg0 = (blockIdx.x * 2 + t) * PT;
    const int n0 = pg0 & (NPB - 1);
    {
      const float4* src = reinterpret_cast<const float4*>(f128g + (size_t)b * 128 * NPB + n0);
      float4* dst = reinterpret_cast<float4*>(A128s);
      for (int i4 = tid; i4 < 128 * (PT / 4); i4 += TPB) {
        const int r = i4 >> 4, q = i4 & 15;
        dst[i4] = src[r * (NPB / 4) + q];
      }
    }
    const int cl = clg[pg0 + lane];
    float acco1[16];
#pragma unroll
    for (int j = 0; j < 16; ++j) acco1[j] = poolco[(o0 + j) * NC + cl];
    __syncthreads();
    for (int c = 0; c < 2; ++c) {
      {  // f3 chunk
        const int oc = c * 64 + g * 8;
        float acc[8];
#pragma unroll
        for (int j = 0; j < 8; ++j) acc[j] = b3s[oc + j];
        accum_lds<128, 8, 128>(acc, A128s, w3s + oc * 128, lane);
#pragma unroll
        for (int j = 0; j < 8; ++j) F3ch[(g * 8 + j) * PT + lane] = relu_(acc[j]);
      }
      __syncthreads();
      accum_lds<64, 16, 256>(acco1, F3ch, wo1 + o0 * 256 + c * 64, lane);
      __syncthreads();
    }
#pragma unroll
    for (int j = 0; j < 16; ++j) A128s[(o0 + j) * PT + lane] = relu_(acco1[j]);  // O1
    __syncthreads();
    {  // o2 + running max
      float acc[16];
#pragma unroll
      for (int j = 0; j < 16; ++j) acc[j] = bo2[o0 + j];
      accum_lds<128, 16, 128>(acc, A128s, wo2 + o0 * 128, lane);
#pragma unroll
      for (int j = 0; j < 16; ++j) omax[j] = fmaxf(omax[j], relu_(acc[j]));
    }
    __syncthreads();
  }
#pragma unroll
  for (int j = 0; j < 16; ++j) {
    float m = omax[j];
#pragma unroll
    for (int off = 32; off; off >>= 1) m = fmaxf(m, __shfl_xor(m, off));
    if (lane == 0)
      atomicMax(reinterpret_cast<unsigned*>(&out[b * 128 + o0 + j]), __float_as_uint(m));
  }
}

extern "C" void kernel_launch(void* const* d_in, const int* in_sizes, int n_in,
                              void* d_out, int out_size, void* d_ws, size_t ws_size,
                              hipStream_t stream) {
  const float* x    = (const float*)d_in[0];
  const int*   cls  = (const int*)d_in[1];
  const float* w_in = (const float*)d_in[2];
  const float* b_in = (const float*)d_in[3];
  const float* w1   = (const float*)d_in[4];
  const float* b1   = (const float*)d_in[5];
  const float* w2   = (const float*)d_in[6];
  const float* b2   = (const float*)d_in[7];
  const float* w3   = (const float*)d_in[8];
  const float* b3   = (const float*)d_in[9];
  const float* wo1  = (const float*)d_in[10];
  const float* bo1  = (const float*)d_in[11];
  const float* wo2  = (const float*)d_in[12];
  const float* bo2  = (const float*)d_in[13];
  float* out = (float*)d_out;

  char* ws = (char*)d_ws;
  float* f128g = (float*)ws;                                  // 8*128*16384 f32 = 64 MB
  float* part0 = (float*)(ws + ((size_t)64 << 20));           // 512*2048 f32 = 4 MB
  float* part1 = part0 + (size_t)NBLK * 2048;
  float* part2 = part1 + (size_t)NBLK * 2048;

  hipMemsetAsync(d_out, 0, 1024 * sizeof(float), stream);

  k0_kern<<<NBLK, TPB, 0, stream>>>(x, cls, w_in, b_in, w1, b1, w2, b2, f128g, part0);
  kmid_kern<<<NBLK, TPB, 0, stream>>>(f128g, part0, part1, cls, w3, b3, w1, b1, w2, b2, 1);
  kmid_kern<<<NBLK, TPB, 0, stream>>>(f128g, part1, part2, cls, w3, b3, w1, b1, w2, b2, 2);
  k3_kern<<<NBLK3, TPB, 0, stream>>>(f128g, part2, cls, w3, b3, wo1, bo1, wo2, bo2, out);
}